// Round 7
// baseline (10324.541 us; speedup 1.0000x reference)
//
#include <hip/hip_runtime.h>
#include <stdint.h>

#define N_PTS 65536
#define DIMS 6
#define NSAMP 2048
#define NGRP 64
#define EMB 512
#define ROWS (NSAMP*NGRP)
#define EPS_BN 1e-5f

#define FIRST_MODE 0

typedef __attribute__((ext_vector_type(8))) short short8;
typedef __attribute__((ext_vector_type(4))) float float4v;
typedef __attribute__((ext_vector_type(4))) unsigned uint4v;

__device__ __forceinline__ unsigned short f2bf(float f) {
  unsigned u = __float_as_uint(f);
  u += 0x7FFFu + ((u >> 16) & 1u);   // RNE
  return (unsigned short)(u >> 16);
}

// ---------------- Threefry-2x32, 20 rounds (JAX-compatible) ----------------
__device__ __forceinline__ void tf2x32(unsigned k0, unsigned k1, unsigned &x0, unsigned &x1) {
  unsigned ks[3] = {k0, k1, k0 ^ k1 ^ 0x1BD11BDAu};
  const unsigned R[8] = {13,15,26,6,17,29,16,24};
  x0 += ks[0]; x1 += ks[1];
#pragma unroll
  for (int g = 0; g < 5; ++g) {
#pragma unroll
    for (int j = 0; j < 4; ++j) {
      unsigned r = R[(g & 1) * 4 + j];
      x0 += x1;
      x1 = (x1 << r) | (x1 >> (32 - r));
      x1 ^= x0;
    }
    x0 += ks[(g + 1) % 3];
    x1 += ks[(g + 2) % 3] + (unsigned)(g + 1);
  }
}

__device__ __forceinline__ int compute_first(unsigned seed) {
  unsigned k0 = 0u, k1 = seed;
  unsigned s0, s1;
#if (FIRST_MODE == 0) || (FIRST_MODE == 1)
  { unsigned a0 = 0u, a1 = 1u; tf2x32(k0, k1, a0, a1); s0 = a0; s1 = a1; }
#else
  { unsigned p0 = 0u, p1 = 2u; tf2x32(k0, k1, p0, p1);
    unsigned q0 = 1u, q1 = 3u; tf2x32(k0, k1, q0, q1);
    s0 = p1; s1 = q1; }
#endif
  unsigned b0 = 0u, b1v = 0u; tf2x32(s0, s1, b0, b1v);
#if (FIRST_MODE == 0) || (FIRST_MODE == 3)
  unsigned bits = b0 ^ b1v;
#else
  unsigned bits = b0;
#endif
  return (int)(bits & 0xFFFFu);
}

// ---------------- geometry ---------------------------------------------------
#define FPSB 16                      // FPS blocks (bid%16==0 -> one XCD if bid%8 RR)
#define MEGA_BLOCKS 256              // 16 FPS + 240 workers; 1 block/CU (LDS-forced)
#define FPS_PPT 4                    // 65536 / (16*1024)
#define GB_CAND 512
#define H1B_S 520                    // bf16 h1 LDS row stride (bank-benign)
#define MEGA_LDS 90112               // > 80 KB -> hardware cannot co-schedule 2 blocks/CU
#define FAST_TRIES 64                // bounded mirror polls before sticky agent fallback
#define WARMUP_ITS 4                 // agent-path iterations before first mirror probe
#define RING_W 256                   // one slot per wave (16 blocks x 16 waves)

// DPP max step: VALU-only cross-lane (no LDS round trip like __shfl).
// bound_ctrl=1 -> invalid source lanes read 0 (identity for unsigned max).
#define DPPMAX(x, ctrl) do { \
  unsigned _m = (unsigned)__builtin_amdgcn_update_dpp(0, (int)(x), (ctrl), 0xf, 0xf, true); \
  (x) = (x) > _m ? (x) : _m; } while (0)

// sc0-only ops: bypass L1, hit this XCD's shared L2 (R4-validated: the 16 FPS
// blocks co-locate on one XCD under bid%16==0 placement).
__device__ __forceinline__ void st_u64_l2(unsigned long long* p, unsigned long long v) {
  asm volatile("global_store_dwordx2 %0, %1, off sc0" :: "v"(p), "v"(v) : "memory");
}
// 4 consecutive u64 slots in two dwordx4 loads, single waitcnt.
__device__ __forceinline__ void ld_slots_l2(const unsigned long long* p,
                                            uint4v &a, uint4v &c) {
  asm volatile("global_load_dwordx4 %0, %2, off sc0\n\t"
               "global_load_dwordx4 %1, %2, off offset:16 sc0\n\t"
               "s_waitcnt vmcnt(0)"
               : "=&v"(a), "=&v"(c) : "v"(p) : "memory");
}

// ---------------- init: xyzw, rings, stats, W2T(bf16), first idx ------------
__global__ __launch_bounds__(256) void k_init(const float* __restrict__ pts,
    const float* __restrict__ W2, const int* __restrict__ seed_arr,
    unsigned long long* __restrict__ slot, float* __restrict__ stats,
    float* __restrict__ st2, unsigned short* __restrict__ W2T,
    float4* __restrict__ xyzw, int* __restrict__ sampled) {
  int tid = blockIdx.x * 256 + threadIdx.x;        // 65536 threads
  if (tid < N_PTS) {
    float x = pts[tid*6], y = pts[tid*6+1], z = pts[tid*6+2];
    float p2 = __fadd_rn(__fadd_rn(__fmul_rn(x,x), __fmul_rn(y,y)), __fmul_rn(z,z));
    xyzw[tid] = make_float4(x, y, z, p2);
  }
#pragma unroll
  for (int i = 0; i < 4; ++i) {      // W2T[c][k] = bf16(W2[k][c]); writes coalesced
    int e = tid + i*65536;
    int c = e >> 9, k = e & 511;
    W2T[e] = f2bf(W2[k*EMB + c]);
  }
  if (tid < 4*RING_W) slot[tid] = 0ull;            // mirror ring + canonical ring
  if (tid < 4*EMB) stats[tid] = 0.f;
  if (tid < 32*1024) st2[tid] = 0.f;               // sliced bn2 stats
  if (tid >= 1 && tid < NSAMP) sampled[tid] = -1;  // sentinel for workers
  if (tid == 0) sampled[0] = compute_first((unsigned)seed_arr[0]);
}

// ---------------- mega: FPS blocks + group/stats worker blocks ---------------
// R7: single-level barrier-free exchange. Every wave publishes its wave-max
// directly (sc0 mirror ring + agent canonical ring, depth-2, iteration-tagged
// values: dist32 | tag16 | (0xFFFF-idx)). Leader wave of each block polls all
// 256 wave slots (4 u64/lane), DPP-reduces, broadcasts via tagged winLDS.
// No __syncthreads in the loop; no LDS block reduce; winner bit-identical.
// Tag semantics make the protocol terminate from ARBITRARY memory state
// (rocprof replay): a slot can only legally hold tag it+1 (ready) or it-1 /
// 0 (stale); any other tag => stale-environment => value treated as 0.
__global__ __launch_bounds__(1024) void k_mega(
    const float4* __restrict__ xyzw, const float* __restrict__ pts,
    const float* __restrict__ W1, const float* __restrict__ b1,
    unsigned long long* __restrict__ slot, int* __restrict__ sampled,
    int* __restrict__ groups, float* __restrict__ gsum, float* __restrict__ gss) {
  extern __shared__ __align__(16) char smraw[];
  const int t = threadIdx.x;
  if ((blockIdx.x & 15) == 0) {
    // ------------------ FPS role ------------------
    volatile int* winLDS = (volatile int*)smraw;                 // [1], tagged
    unsigned long long* mirR = slot;                             // [2][256] sc0
    unsigned long long* canR = slot + 2*RING_W;                  // [2][256] agent
    const int b = blockIdx.x >> 4;                               // 0..15
    const int T = b*1024 + t;                                    // 0..16383
    const int lane = t & 63, wid = t >> 6;
    const int gw = b*16 + wid;                                   // 0..255
    const bool isLead = (wid == 0);
    float px[FPS_PPT], py[FPS_PPT], pz[FPS_PPT], pd[FPS_PPT];
    unsigned nidxu[FPS_PPT];
#pragma unroll
    for (int i = 0; i < FPS_PPT; ++i) {
      float4 p = xyzw[T + 16384*i];
      px[i] = p.x; py[i] = p.y; pz[i] = p.z; pd[i] = __builtin_inff();
      nidxu[i] = 0xFFFFFFFFu - (unsigned)(T + 16384*i);
    }
    if (t == 0) winLDS[0] = 0;
    int last = sampled[0] & 0xFFFF;
    bool slow = false;                   // wave-uniform sticky fallback flag
    if (isLead) __builtin_amdgcn_s_setprio(3);
    __syncthreads();                     // once, pre-loop
    for (int it = 0; it < NSAMP-1; ++it) {
      const unsigned tag = (unsigned)(it + 1);
      float4 cc = xyzw[last];
      unsigned long long best = 1ull;
#pragma unroll
      for (int i = 0; i < FPS_PPT; ++i) {
        float dx = __fsub_rn(px[i], cc.x);
        float dy = __fsub_rn(py[i], cc.y);
        float dz = __fsub_rn(pz[i], cc.z);
        float d = __fadd_rn(__fadd_rn(__fmul_rn(dx,dx), __fmul_rn(dy,dy)), __fmul_rn(dz,dz));
        pd[i] = fminf(pd[i], d);
        unsigned long long pk = ((unsigned long long)__float_as_uint(pd[i]) << 32)
                              | (unsigned long long)nidxu[i];
        best = best > pk ? best : pk;
      }
      // wave reduce: DPP prefix-max on u32 dist bits -> lane63 -> SGPR;
      // exact u64 butterfly only on (rare) cross-lane distance ties.
      unsigned myd = (unsigned)(best >> 32);
      unsigned r = myd;
      DPPMAX(r, 0x111);   // row_shr:1
      DPPMAX(r, 0x112);   // row_shr:2
      DPPMAX(r, 0x114);   // row_shr:4
      DPPMAX(r, 0x118);   // row_shr:8
      DPPMAX(r, 0x142);   // row_bcast:15
      DPPMAX(r, 0x143);   // row_bcast:31
      unsigned bd = (unsigned)__builtin_amdgcn_readlane((int)r, 63);
      unsigned long long tie = __ballot(myd == bd);
      unsigned long long wbest;
      if (__popcll(tie) == 1) {
        int wl = (int)__builtin_ctzll(tie);
        unsigned lo = (unsigned)__builtin_amdgcn_readlane((int)(unsigned)best, wl);
        wbest = ((unsigned long long)bd << 32) | (unsigned long long)lo;
      } else {
        wbest = best;
#pragma unroll
        for (int off = 32; off >= 1; off >>= 1) {
          unsigned long long o = __shfl_xor(wbest, off, 64);
          wbest = wbest > o ? wbest : o;
        }
      }
      // publish wave-max immediately (no intra-block sync):
      // value = dist32 | tag16 | (0xFFFF - idx16); same ordering, tagged.
      unsigned widx = 0xFFFFFFFFu - (unsigned)wbest;          // winner idx
      unsigned long long sv = ((wbest >> 32) << 32)
                            | ((unsigned long long)(tag & 0xFFFFu) << 16)
                            | (unsigned long long)(0xFFFFu - (widx & 0xFFFFu));
      if (lane == 0) {
        st_u64_l2(&mirR[(it & 1)*RING_W + gw], sv);
        __hip_atomic_store(&canR[(it & 1)*RING_W + gw], sv,
                           __ATOMIC_RELAXED, __HIP_MEMORY_SCOPE_AGENT);
      }
      if (isLead) {
        // poll all 256 wave slots: 4 u64 per lane.
        const int pg = (it & 1)*RING_W + lane*4;
        const unsigned tagw = tag & 0xFFFFu;
        const unsigned staleT = (it >= 2) ? (unsigned)((it - 1) & 0xFFFF) : 0u;
        unsigned long long v0, v1, v2, v3;
        bool useFast = (!slow) && (it >= WARMUP_ITS);
        int tries = 0;
        for (;;) {
          if (useFast) {
            uint4v a, c;
            ld_slots_l2(&mirR[pg], a, c);
            v0 = ((unsigned long long)a[1] << 32) | a[0];
            v1 = ((unsigned long long)a[3] << 32) | a[2];
            v2 = ((unsigned long long)c[1] << 32) | c[0];
            v3 = ((unsigned long long)c[3] << 32) | c[2];
          } else {
            v0 = __hip_atomic_load(&canR[pg+0], __ATOMIC_RELAXED, __HIP_MEMORY_SCOPE_AGENT);
            v1 = __hip_atomic_load(&canR[pg+1], __ATOMIC_RELAXED, __HIP_MEMORY_SCOPE_AGENT);
            v2 = __hip_atomic_load(&canR[pg+2], __ATOMIC_RELAXED, __HIP_MEMORY_SCOPE_AGENT);
            v3 = __hip_atomic_load(&canR[pg+3], __ATOMIC_RELAXED, __HIP_MEMORY_SCOPE_AGENT);
          }
          unsigned t0 = ((unsigned)v0 >> 16) & 0xFFFFu;
          unsigned t1 = ((unsigned)v1 >> 16) & 0xFFFFu;
          unsigned t2 = ((unsigned)v2 >> 16) & 0xFFFFu;
          unsigned t3 = ((unsigned)v3 >> 16) & 0xFFFFu;
          bool anystale = (t0 == staleT) || (t1 == staleT) ||
                          (t2 == staleT) || (t3 == staleT);
          if (__ballot(anystale) == 0ull) {
            if (t0 != tagw) v0 = 0ull;     // alien (replay garbage) -> ignore
            if (t1 != tagw) v1 = 0ull;
            if (t2 != tagw) v2 = 0ull;
            if (t3 != tagw) v3 = 0ull;
            break;
          }
          if (useFast && ++tries >= FAST_TRIES) { slow = true; useFast = false; }
        }
        // reduce 256: local max of 4, then DPP on dist bits + ballot.
        unsigned long long m01 = v0 > v1 ? v0 : v1;
        unsigned long long m23 = v2 > v3 ? v2 : v3;
        unsigned long long lm  = m01 > m23 ? m01 : m23;
        unsigned ld_ = (unsigned)(lm >> 32);
        unsigned r2 = ld_;
        DPPMAX(r2, 0x111);
        DPPMAX(r2, 0x112);
        DPPMAX(r2, 0x114);
        DPPMAX(r2, 0x118);
        DPPMAX(r2, 0x142);
        DPPMAX(r2, 0x143);
        unsigned bd2 = (unsigned)__builtin_amdgcn_readlane((int)r2, 63);
        unsigned long long tie2 = __ballot(ld_ == bd2);
        unsigned long long gbest;
        if (__popcll(tie2) == 1) {
          int wl2 = (int)__builtin_ctzll(tie2);
          unsigned lo2 = (unsigned)__builtin_amdgcn_readlane((int)(unsigned)lm, wl2);
          gbest = ((unsigned long long)bd2 << 32) | (unsigned long long)lo2;
        } else {
          gbest = lm;
#pragma unroll
          for (int off = 32; off >= 1; off >>= 1) {
            unsigned long long o = __shfl_xor(gbest, off, 64);
            gbest = gbest > o ? gbest : o;
          }
          gbest = __shfl(gbest, 0, 64);
        }
        int win = (int)(0xFFFFu - ((unsigned)gbest & 0xFFFFu));
        if (lane == 0) {
          if (b == 0)
            __hip_atomic_store((unsigned*)&sampled[it+1], (unsigned)win,
                               __ATOMIC_RELAXED, __HIP_MEMORY_SCOPE_AGENT);
          winLDS[0] = (int)((tag << 16) | (unsigned)win);
        }
        last = win;
      } else {
        __builtin_amdgcn_s_setprio(0);
        int w = winLDS[0];
        while (((unsigned)w >> 16) != tag) { __builtin_amdgcn_s_sleep(1); w = winLDS[0]; }
        __builtin_amdgcn_s_setprio(1);
        last = w & 0xFFFF;
      }
    }
  } else {
    // ------------------ worker role: group + bn1 stats ------------------
    unsigned* hist  = (unsigned*)smraw;              // 8192
    unsigned* scan  = (unsigned*)(smraw + 32768);    // 1024
    unsigned* candK = (unsigned*)(smraw + 36864);    // 512
    int*      candI = (int*)(smraw + 38912);         // 512
    float*    feat  = (float*)(smraw + 40960);       // 768
    float*    cf    = (float*)(smraw + 44032);       // 8
    unsigned* ctl   = (unsigned*)(smraw + 44064);    // outcnt, candcnt
    volatile int* binfo = (volatile int*)(smraw + 44080); // B, bef, sid
    const int wkr = blockIdx.x - 1 - (blockIdx.x >> 4);   // 0..239 (bid%16!=0)
    for (int s = wkr; s < NSAMP; s += MEGA_BLOCKS - FPSB) {
      if (t == 0) {
        unsigned v = __hip_atomic_load((const unsigned*)&sampled[s],
                        __ATOMIC_RELAXED, __HIP_MEMORY_SCOPE_AGENT);
        while (v == 0xFFFFFFFFu) {
          __builtin_amdgcn_s_sleep(64);
          v = __hip_atomic_load((const unsigned*)&sampled[s],
                  __ATOMIC_RELAXED, __HIP_MEMORY_SCOPE_AGENT);
        }
        binfo[2] = (int)(v & 0xFFFFu);
        ctl[0] = 0u; ctl[1] = 0u;
      }
      for (int k = t; k < 8192; k += 1024) hist[k] = 0u;
      __syncthreads();
      const int sid = binfo[2];
      float4 c4 = xyzw[sid];
      const float cx=c4.x, cy=c4.y, cz=c4.z, c2=c4.w;
      for (int i = 0; i < N_PTS/1024; ++i) {
        int j = i*1024 + t;
        float4 p = xyzw[j];
        float dot = __fadd_rn(__fadd_rn(__fmul_rn(cx,p.x),__fmul_rn(cy,p.y)),__fmul_rn(cz,p.z));
        float d = __fsub_rn(__fadd_rn(c2, p.w), __fmul_rn(2.0f, dot));
        unsigned kb = __float_as_uint(d);
        kb ^= ((unsigned)((int)kb >> 31)) | 0x80000000u;
        atomicAdd(&hist[kb >> 19], 1u);
      }
      __syncthreads();
      unsigned ch = 0u;
      for (int k = 0; k < 8; ++k) ch += hist[t*8 + k];
      scan[t] = ch;
      __syncthreads();
      for (int off = 1; off < 1024; off <<= 1) {
        unsigned vv = (t >= off) ? scan[t - off] : 0u;
        __syncthreads();
        scan[t] += vv;
        __syncthreads();
      }
      unsigned inc = scan[t], before = inc - ch;
      if (before < NGRP && inc >= NGRP) {
        unsigned c = before;
        for (int k = 0; k < 8; ++k) {
          unsigned nb = hist[t*8 + k];
          if (c + nb >= NGRP) { binfo[0] = t*8 + k; binfo[1] = (int)c; break; }
          c += nb;
        }
      }
      __syncthreads();
      const unsigned B = (unsigned)binfo[0];
      const int bef = binfo[1];
      for (int i = 0; i < N_PTS/1024; ++i) {
        int j = i*1024 + t;
        float4 p = xyzw[j];
        float dot = __fadd_rn(__fadd_rn(__fmul_rn(cx,p.x),__fmul_rn(cy,p.y)),__fmul_rn(cz,p.z));
        float d = __fsub_rn(__fadd_rn(c2, p.w), __fmul_rn(2.0f, dot));
        unsigned kb = __float_as_uint(d);
        kb ^= ((unsigned)((int)kb >> 31)) | 0x80000000u;
        unsigned bin = kb >> 19;
        if (bin < B) {
          unsigned pos = atomicAdd(&ctl[0], 1u);
          groups[s*NGRP + pos] = j;
        } else if (bin == B) {
          unsigned ci = atomicAdd(&ctl[1], 1u);
          if (ci < GB_CAND) { candK[ci] = kb; candI[ci] = j; }
        }
      }
      __syncthreads();
      int M = ctl[1] < GB_CAND ? (int)ctl[1] : GB_CAND;
      int need = NGRP - bef;
      for (int c = t; c < M; c += 1024) {
        unsigned mk = candK[c]; int mi = candI[c];
        int rank = 0;
        for (int q = 0; q < M; ++q) {
          unsigned qk = candK[q];
          rank += (qk < mk || (qk == mk && candI[q] < mi)) ? 1 : 0;
        }
        if (rank < need) {
          unsigned pos = atomicAdd(&ctl[0], 1u);
          groups[s*NGRP + pos] = candI[c];
        }
      }
      __syncthreads();
      if (t == 0) {
        while (ctl[0] < NGRP) { groups[s*NGRP + ctl[0]] = 0; ctl[0]++; }
      }
      __syncthreads();
      if (t < DIMS) cf[t] = pts[sid*6 + t];
      __syncthreads();
      if (t < NGRP) {
        int g = groups[s*NGRP + t];
#pragma unroll
        for (int k = 0; k < DIMS; ++k) {
          float v = pts[g*6 + k];
          feat[t*12 + k] = v - cf[k];
          feat[t*12 + 6 + k] = v;
        }
      }
      __syncthreads();
      if (t < EMB) {
        float w[12];
#pragma unroll
        for (int k = 0; k < 12; ++k) w[k] = W1[k*EMB + t];
        float b = b1[t];
        float sum = 0.f, ss = 0.f;
        for (int r = 0; r < NGRP; ++r) {
          float y = b;
#pragma unroll
          for (int k = 0; k < 12; ++k) y += feat[r*12+k] * w[k];
          sum += y; ss += y*y;
        }
        atomicAdd(&gsum[t], sum);
        atomicAdd(&gss[t], ss);
      }
      __syncthreads();   // smraw reused next s
    }
  }
}

// ---------------- bn1 finalize ----------------------------------------------
__global__ __launch_bounds__(EMB) void k_finalize(const float* __restrict__ gsum,
    const float* __restrict__ gss, const float* __restrict__ scale,
    const float* __restrict__ bias, float* __restrict__ ac) {
  int c = threadIdx.x;
  float inv = 1.f / (float)ROWS;
  float mean = gsum[c] * inv;
  float var = gss[c] * inv - mean*mean;
  var = var < 0.f ? 0.f : var;
  float a = scale[c] * rsqrtf(var + EPS_BN);
  ac[c] = a; ac[EMB + c] = bias[c] - mean * a;
}

// ---------------- bn2 finalize from 32-sliced stats -------------------------
__global__ __launch_bounds__(EMB) void k_finalize2(const float* __restrict__ st2,
    const float* __restrict__ scale, const float* __restrict__ bias,
    float* __restrict__ ac) {
  int c = threadIdx.x;
  float sum = 0.f, ss = 0.f;
  for (int i = 0; i < 32; ++i) {
    sum += st2[i*1024 + c];
    ss  += st2[i*1024 + 512 + c];
  }
  float inv = 1.f / (float)ROWS;
  float mean = sum * inv;
  float var = ss * inv - mean*mean;
  var = var < 0.f ? 0.f : var;
  float a = scale[c] * rsqrtf(var + EPS_BN);
  ac[c] = a; ac[EMB + c] = bias[c] - mean * a;
}

// ---------------- fused MLP: fp32 GEMM1 -> bf16 MFMA GEMM2 ------------------
__global__ __launch_bounds__(512, 4) void k_mlp(const float* __restrict__ pts,
    const int* __restrict__ sampled, const int* __restrict__ groups,
    const float* __restrict__ W1, const float* __restrict__ b1,
    const float* __restrict__ ac1, const unsigned short* __restrict__ W2T,
    const float* __restrict__ b2, const float* __restrict__ scale2,
    float* __restrict__ st2, float* __restrict__ y2sel) {
  const int s = blockIdx.x, t = threadIdx.x;
  extern __shared__ __align__(16) char smc[];
  float* feat = (float*)smc;                       // 768 f
  float* cf   = (float*)(smc + 3072);              // 8 f
  unsigned short* h1b = (unsigned short*)(smc + 3104);  // 64 x 520 bf16
  if (t < DIMS) cf[t] = pts[(sampled[s] & 0xFFFF)*6 + t];
  __syncthreads();
  if (t < NGRP) {
    int g = groups[s*NGRP + t];
#pragma unroll
    for (int k = 0; k < DIMS; ++k) {
      float v = pts[g*6 + k];
      feat[t*12+k]   = v - cf[k];
      feat[t*12+6+k] = v;
    }
  }
  __syncthreads();
  {
    float w[12];
#pragma unroll
    for (int k = 0; k < 12; ++k) w[k] = W1[k*EMB + t];
    float b = b1[t], a1 = ac1[t], c1 = ac1[EMB + t];
    for (int r = 0; r < NGRP; ++r) {
      float y = b;
#pragma unroll
      for (int k = 0; k < 12; ++k) y += feat[r*12+k] * w[k];
      float hv = a1*y + c1;
      h1b[r*H1B_S + t] = f2bf(hv > 0.f ? hv : 0.f);
    }
  }
  __syncthreads();
  const int lane = t & 63, w = t >> 6;
  const int quad = lane >> 4, l16 = lane & 15;
  float4v acc[4][4];
#pragma unroll
  for (int nt = 0; nt < 4; ++nt) {
    float bv = b2[(w*4+nt)*16 + l16];
#pragma unroll
    for (int mt = 0; mt < 4; ++mt)
      acc[nt][mt] = (float4v){bv, bv, bv, bv};
  }
  for (int kc = 0; kc < 16; ++kc) {
    const int kb = kc*32 + quad*8;
    short8 af[4];
#pragma unroll
    for (int mt = 0; mt < 4; ++mt)
      af[mt] = *(const short8*)&h1b[(mt*16 + l16)*H1B_S + kb];
#pragma unroll
    for (int nt = 0; nt < 4; ++nt) {
      const int c = (w*4+nt)*16 + l16;
      short8 bf = *(const short8*)&W2T[c*EMB + kb];
#pragma unroll
      for (int mt = 0; mt < 4; ++mt)
        acc[nt][mt] = __builtin_amdgcn_mfma_f32_16x16x32_bf16(af[mt], bf, acc[nt][mt], 0, 0, 0);
    }
  }
#pragma unroll
  for (int nt = 0; nt < 4; ++nt) {
    float sm_ = 0.f, ss_ = 0.f, mx = -__builtin_inff(), mn = __builtin_inff();
#pragma unroll
    for (int mt = 0; mt < 4; ++mt)
#pragma unroll
      for (int i = 0; i < 4; ++i) {
        float v = acc[nt][mt][i];
        sm_ += v; ss_ += v*v;
        mx = fmaxf(mx, v); mn = fminf(mn, v);
      }
#pragma unroll
    for (int off = 16; off <= 32; off <<= 1) {
      sm_ += __shfl_xor(sm_, off, 64);
      ss_ += __shfl_xor(ss_, off, 64);
      mx = fmaxf(mx, __shfl_xor(mx, off, 64));
      mn = fminf(mn, __shfl_xor(mn, off, 64));
    }
    if (quad == 0) {
      int c = (w*4+nt)*16 + l16;
      atomicAdd(&st2[(s & 31)*1024 + c], sm_);
      atomicAdd(&st2[(s & 31)*1024 + 512 + c], ss_);
      y2sel[s*EMB + c] = (scale2[c] >= 0.f) ? mx : mn;
    }
  }
}

// ---------------- epilogue: bn2+relu on pooled extremum ---------------------
__global__ __launch_bounds__(256) void k_out(const float* __restrict__ y2sel,
    const float* __restrict__ ac2, float* __restrict__ out) {
  int i = blockIdx.x*256 + threadIdx.x;
  int c = i & (EMB-1);
  float a = ac2[c], cc = ac2[EMB + c];
  float v = a*y2sel[i] + cc;
  out[i] = v > 0.f ? v : 0.f;
}

extern "C" void kernel_launch(void* const* d_in, const int* in_sizes, int n_in,
                              void* d_out, int out_size, void* d_ws, size_t ws_size,
                              hipStream_t stream) {
  const float* pts    = (const float*)d_in[0];
  const float* W1     = (const float*)d_in[1];
  const float* b1     = (const float*)d_in[2];
  const float* scale1 = (const float*)d_in[3];
  const float* bias1  = (const float*)d_in[4];
  const float* W2     = (const float*)d_in[5];
  const float* b2     = (const float*)d_in[6];
  const float* scale2 = (const float*)d_in[7];
  const float* bias2  = (const float*)d_in[8];
  const int*   seed   = (const int*)d_in[9];
  float* out = (float*)d_out;

  char* ws = (char*)d_ws;
  int*    sampled = (int*)(ws);
  int*    groups  = (int*)(ws + 8192);
  float4* xyzw    = (float4*)(ws + 532480);
  float*  stats   = (float*)(ws + 1581056);
  float* gsum1 = stats, *gss1 = stats + 512;
  float*  ac1     = (float*)(ws + 1589248);
  float*  ac2     = (float*)(ws + 1593344);
  float*  y2sel   = (float*)(ws + 1597440);          // 4 MB
  // rings alias y2sel (disjoint lifetime): 4*256 u64 = 8 KB << 4 MB
  unsigned long long* slot = (unsigned long long*)(ws + 1597440);
  unsigned short* W2T = (unsigned short*)(ws + 5791744);   // 512 KB bf16
  float* st2      = (float*)(ws + 6316032);          // 32 x 1024 sliced bn2 stats

  k_init<<<256, 256, 0, stream>>>(pts, W2, seed, slot, stats, st2, W2T, xyzw, sampled);
  k_mega<<<MEGA_BLOCKS, 1024, MEGA_LDS, stream>>>(xyzw, pts, W1, b1, slot, sampled,
                                                  groups, gsum1, gss1);
  k_finalize<<<1, EMB, 0, stream>>>(gsum1, gss1, scale1, bias1, ac1);
  size_t mlp_lds = 3104 + (size_t)NGRP * H1B_S * sizeof(unsigned short);  // ~68 KB
  k_mlp<<<NSAMP, 512, mlp_lds, stream>>>(pts, sampled, groups, W1, b1, ac1,
                                         W2T, b2, scale2, st2, y2sel);
  k_finalize2<<<1, EMB, 0, stream>>>(st2, scale2, bias2, ac2);
  k_out<<<(out_size+255)/256, 256, 0, stream>>>(y2sel, ac2, out);
}

// Round 8
// 3799.762 us; speedup vs baseline: 2.7172x; 2.7172x over previous
//
#include <hip/hip_runtime.h>
#include <stdint.h>

#define N_PTS 65536
#define DIMS 6
#define NSAMP 2048
#define NGRP 64
#define EMB 512
#define ROWS (NSAMP*NGRP)
#define EPS_BN 1e-5f

#define FIRST_MODE 0

typedef __attribute__((ext_vector_type(8))) short short8;
typedef __attribute__((ext_vector_type(4))) float float4v;

__device__ __forceinline__ unsigned short f2bf(float f) {
  unsigned u = __float_as_uint(f);
  u += 0x7FFFu + ((u >> 16) & 1u);   // RNE
  return (unsigned short)(u >> 16);
}

// ---------------- Threefry-2x32, 20 rounds (JAX-compatible) ----------------
__device__ __forceinline__ void tf2x32(unsigned k0, unsigned k1, unsigned &x0, unsigned &x1) {
  unsigned ks[3] = {k0, k1, k0 ^ k1 ^ 0x1BD11BDAu};
  const unsigned R[8] = {13,15,26,6,17,29,16,24};
  x0 += ks[0]; x1 += ks[1];
#pragma unroll
  for (int g = 0; g < 5; ++g) {
#pragma unroll
    for (int j = 0; j < 4; ++j) {
      unsigned r = R[(g & 1) * 4 + j];
      x0 += x1;
      x1 = (x1 << r) | (x1 >> (32 - r));
      x1 ^= x0;
    }
    x0 += ks[(g + 1) % 3];
    x1 += ks[(g + 2) % 3] + (unsigned)(g + 1);
  }
}

__device__ __forceinline__ int compute_first(unsigned seed) {
  unsigned k0 = 0u, k1 = seed;
  unsigned s0, s1;
#if (FIRST_MODE == 0) || (FIRST_MODE == 1)
  { unsigned a0 = 0u, a1 = 1u; tf2x32(k0, k1, a0, a1); s0 = a0; s1 = a1; }
#else
  { unsigned p0 = 0u, p1 = 2u; tf2x32(k0, k1, p0, p1);
    unsigned q0 = 1u, q1 = 3u; tf2x32(k0, k1, q0, q1);
    s0 = p1; s1 = q1; }
#endif
  unsigned b0 = 0u, b1v = 0u; tf2x32(s0, s1, b0, b1v);
#if (FIRST_MODE == 0) || (FIRST_MODE == 3)
  unsigned bits = b0 ^ b1v;
#else
  unsigned bits = b0;
#endif
  return (int)(bits & 0xFFFFu);
}

// ---------------- geometry ---------------------------------------------------
#define FPSB 16                      // FPS blocks (bid%16==0 -> one XCD if bid%8 RR)
#define MEGA_BLOCKS 256              // 16 FPS + 240 workers; 1 block/CU (LDS-forced)
#define GB_CAND 512
#define H1B_S 520                    // bf16 h1 LDS row stride (bank-benign)
#define MEGA_LDS 90112               // > 80 KB -> hardware cannot co-schedule 2 blocks/CU
#define FAST_TRIES 64                // bounded mirror polls before sticky agent fallback
#define WARMUP_ITS 4                 // agent-path iterations before first mirror probe
#define SLOTS ((NSAMP-1)*FPSB)       // 32752 u64 per array (slot + mirror)

// DPP max step: VALU-only cross-lane (no LDS round trip like __shfl).
// bound_ctrl=1 -> invalid source lanes read 0 (identity for unsigned max).
#define DPPMAX(x, ctrl) do { \
  unsigned _m = (unsigned)__builtin_amdgcn_update_dpp(0, (int)(x), (ctrl), 0xf, 0xf, true); \
  (x) = (x) > _m ? (x) : _m; } while (0)

// sc0-only ops: bypass L1, hit this XCD's shared L2 (R4-validated: the 16 FPS
// blocks co-locate on one XCD under bid%16==0 placement; mirror poll runs at
// L2 latency). Warm-up gate + bounded sticky fallback keep deadlock impossible
// under ANY wrong mapping/cache assumption.
__device__ __forceinline__ void st_u64_l2(unsigned long long* p, unsigned long long v) {
  asm volatile("global_store_dwordx2 %0, %1, off sc0" :: "v"(p), "v"(v) : "memory");
}
__device__ __forceinline__ unsigned long long ld_u64_l2(const unsigned long long* p) {
  unsigned long long r;
  asm volatile("global_load_dwordx2 %0, %1, off sc0\n\ts_waitcnt vmcnt(0)"
               : "=&v"(r) : "v"(p) : "memory");
  return r;
}

// ---------------- init: xyzw, slots+mirror, stats, W2T(bf16), first idx -----
__global__ __launch_bounds__(256) void k_init(const float* __restrict__ pts,
    const float* __restrict__ W2, const int* __restrict__ seed_arr,
    unsigned long long* __restrict__ slot, float* __restrict__ stats,
    float* __restrict__ st2, unsigned short* __restrict__ W2T,
    float4* __restrict__ xyzw, int* __restrict__ sampled) {
  int tid = blockIdx.x * 256 + threadIdx.x;        // 65536 threads
  if (tid < N_PTS) {
    float x = pts[tid*6], y = pts[tid*6+1], z = pts[tid*6+2];
    float p2 = __fadd_rn(__fadd_rn(__fmul_rn(x,x), __fmul_rn(y,y)), __fmul_rn(z,z));
    xyzw[tid] = make_float4(x, y, z, p2);
  }
#pragma unroll
  for (int i = 0; i < 4; ++i) {      // W2T[c][k] = bf16(W2[k][c]); writes coalesced
    int e = tid + i*65536;
    int c = e >> 9, k = e & 511;
    W2T[e] = f2bf(W2[k*EMB + c]);
  }
  if (tid < 2*SLOTS) slot[tid] = 0ull;             // canonical slots + mirror
  if (tid < 4*EMB) stats[tid] = 0.f;
  if (tid < 32*1024) st2[tid] = 0.f;               // sliced bn2 stats
  if (tid >= 1 && tid < NSAMP) sampled[tid] = -1;  // sentinel for workers
  if (tid == 0) sampled[0] = compute_first((unsigned)seed_arr[0]);
}

// ---------------- mega: FPS blocks + group/stats worker blocks ---------------
// R8 = proven R6 protocol (two-level exchange: DPP wave reduce -> LDS
// atomicMax pre-barrier -> leader mirror+agent store -> warm-up-gated sticky
// L2 poll -> DPP 16-reduce -> winLDS broadcast) with ONE change: the leader
// wave owns ZERO points. Its 256 points go to waves 1..4 (one extra coalesced
// point per lane); waves 5..15 carry a dummy slot (key 0, never wins). The
// leader's serial tail (poll+reduce+broadcast) no longer has a distance
// update appended to it, removing ~500-700cy from the per-iteration chain.
__global__ __launch_bounds__(1024) void k_mega(
    const float4* __restrict__ xyzw, const float* __restrict__ pts,
    const float* __restrict__ W1, const float* __restrict__ b1,
    unsigned long long* __restrict__ slot, int* __restrict__ sampled,
    int* __restrict__ groups, float* __restrict__ gsum, float* __restrict__ gss) {
  extern __shared__ __align__(16) char smraw[];
  const int t = threadIdx.x;
  unsigned long long* mirror = slot + SLOTS;
  if ((blockIdx.x & 15) == 0) {
    // ------------------ FPS role ------------------
    unsigned long long* blkmax = (unsigned long long*)smraw;     // [2] ds_max targets
    volatile int* winLDS = (volatile int*)(smraw + 256);         // [2]
    const int b = blockIdx.x >> 4;                               // 0..15
    const int lane = t & 63, wid = t >> 6;
    float px[5], py[5], pz[5], pd[5];
    unsigned nidxu[5];
    if (wid > 0) {
      const int T = b*1024 + t;          // t>=64: offsets 64..1023 of each slice
#pragma unroll
      for (int i = 0; i < 4; ++i) {
        float4 p = xyzw[T + 16384*i];
        px[i] = p.x; py[i] = p.y; pz[i] = p.z; pd[i] = __builtin_inff();
        nidxu[i] = 0xFFFFFFFFu - (unsigned)(T + 16384*i);
      }
      if (wid <= 4) {                    // waves 1..4 absorb leader's 256 points
        int e = b*1024 + lane + 16384*(wid - 1);   // coalesced per wave
        float4 p = xyzw[e];
        px[4] = p.x; py[4] = p.y; pz[4] = p.z; pd[4] = __builtin_inff();
        nidxu[4] = 0xFFFFFFFFu - (unsigned)e;
      } else {                           // dummy slot: key stays 0, never wins
        px[4] = 0.f; py[4] = 0.f; pz[4] = 0.f; pd[4] = 0.f;
        nidxu[4] = 0u;
      }
    }
    if (t == 0) { winLDS[0] = -1; winLDS[1] = -1; blkmax[0] = 0ull; blkmax[1] = 0ull; }
    int last = sampled[0] & 0xFFFF;
    bool slowlink = false;               // sticky per-lane fallback flag
    if (wid == 0) __builtin_amdgcn_s_setprio(3);   // leader wave owns the chain
    __syncthreads();
    for (int it = 0; it < NSAMP-1; ++it) {
      const int p = it & 1;
      if (wid > 0) {
        float4 cc = xyzw[last];
        unsigned long long best = 1ull;
#pragma unroll
        for (int i = 0; i < 5; ++i) {
          float dx = __fsub_rn(px[i], cc.x);
          float dy = __fsub_rn(py[i], cc.y);
          float dz = __fsub_rn(pz[i], cc.z);
          float d = __fadd_rn(__fadd_rn(__fmul_rn(dx,dx), __fmul_rn(dy,dy)), __fmul_rn(dz,dz));
          pd[i] = fminf(pd[i], d);
          unsigned long long pk = ((unsigned long long)__float_as_uint(pd[i]) << 32)
                                | (unsigned long long)nidxu[i];
          best = best > pk ? best : pk;
        }
        // wave reduce: DPP prefix-max on u32 dist bits -> lane63 -> SGPR;
        // exact u64 butterfly only on (rare) cross-lane distance ties.
        unsigned myd = (unsigned)(best >> 32);
        unsigned r = myd;
        DPPMAX(r, 0x111);   // row_shr:1
        DPPMAX(r, 0x112);   // row_shr:2
        DPPMAX(r, 0x114);   // row_shr:4
        DPPMAX(r, 0x118);   // row_shr:8
        DPPMAX(r, 0x142);   // row_bcast:15
        DPPMAX(r, 0x143);   // row_bcast:31
        unsigned bd = (unsigned)__builtin_amdgcn_readlane((int)r, 63);
        unsigned long long tie = __ballot(myd == bd);
        unsigned long long wbest;
        if (__popcll(tie) == 1) {
          int wl = (int)__builtin_ctzll(tie);
          unsigned lo = (unsigned)__builtin_amdgcn_readlane((int)(unsigned)best, wl);
          wbest = ((unsigned long long)bd << 32) | (unsigned long long)lo;
        } else {
          wbest = best;
#pragma unroll
          for (int off = 32; off >= 1; off >>= 1) {
            unsigned long long o = __shfl_xor(wbest, off, 64);
            wbest = wbest > o ? wbest : o;
          }
        }
        if (lane == 0) atomicMax(&blkmax[p], wbest);   // block reduce, pre-barrier
      }
      __syncthreads();
      if (wid == 0) {
        if (lane == 0) {
          winLDS[1-p] = -1;                // safe: all waves past prev spin
          unsigned long long m = blkmax[p];
          blkmax[p] = 0ull;                // re-arm for it+2
          st_u64_l2(&mirror[it*FPSB + b], m);        // fast: local-L2 mirror
          __hip_atomic_store(&slot[it*FPSB + b], m,
                             __ATOMIC_RELAXED, __HIP_MEMORY_SCOPE_AGENT);
        }
        unsigned long long v = 0ull;
        if (lane < FPSB) {
          unsigned long long* spm = &mirror[it*FPSB + lane];
          unsigned long long* sp  = &slot[it*FPSB + lane];
          if (it >= WARMUP_ITS && !slowlink) {
            int tries = 0;
            do { v = ld_u64_l2(spm); } while (v == 0ull && ++tries < FAST_TRIES);
            if (v == 0ull) slowlink = true;
          }
          if (v == 0ull) {                   // warm-up or sticky fallback
            do { v = __hip_atomic_load(sp, __ATOMIC_RELAXED, __HIP_MEMORY_SCOPE_AGENT); }
            while (v == 0ull);
          }
        }
        // 16-lane reduce: DPP row prefix-max -> lane15 -> SGPR; exact
        // u64 butterfly fallback on distance ties.
        unsigned pd32 = (unsigned)(v >> 32);
        unsigned r2 = pd32;
        DPPMAX(r2, 0x111);
        DPPMAX(r2, 0x112);
        DPPMAX(r2, 0x114);
        DPPMAX(r2, 0x118);
        unsigned bd2 = (unsigned)__builtin_amdgcn_readlane((int)r2, 15);
        unsigned long long tie2 = __ballot((lane < FPSB) && (pd32 == bd2));
        if (__popcll(tie2) == 1) {
          int wl2 = (int)__builtin_ctzll(tie2);
          unsigned lo2 = (unsigned)__builtin_amdgcn_readlane((int)(unsigned)v, wl2);
          v = ((unsigned long long)bd2 << 32) | (unsigned long long)lo2;
        } else {
#pragma unroll
          for (int off = 8; off >= 1; off >>= 1) {
            unsigned long long o = __shfl_xor(v, off, 64);
            v = v > o ? v : o;
          }
          v = __shfl(v, 0, 64);
        }
        int win = (int)(0xFFFFFFFFu - (unsigned)(v & 0xFFFFFFFFull)) & 0xFFFF;
        if (lane == 0) {
          if (b == 0)
            __hip_atomic_store((unsigned*)&sampled[it+1], (unsigned)win,
                               __ATOMIC_RELAXED, __HIP_MEMORY_SCOPE_AGENT);
          winLDS[p] = win;
        }
        last = win;
      } else {
        __builtin_amdgcn_s_setprio(0);
        int w = winLDS[p];
        while (w == -1) { __builtin_amdgcn_s_sleep(1); w = winLDS[p]; }
        __builtin_amdgcn_s_setprio(1);
        last = w;
      }
    }
  } else {
    // ------------------ worker role: group + bn1 stats ------------------
    unsigned* hist  = (unsigned*)smraw;              // 8192
    unsigned* scan  = (unsigned*)(smraw + 32768);    // 1024
    unsigned* candK = (unsigned*)(smraw + 36864);    // 512
    int*      candI = (int*)(smraw + 38912);         // 512
    float*    feat  = (float*)(smraw + 40960);       // 768
    float*    cf    = (float*)(smraw + 44032);       // 8
    unsigned* ctl   = (unsigned*)(smraw + 44064);    // outcnt, candcnt
    volatile int* binfo = (volatile int*)(smraw + 44080); // B, bef, sid
    const int wkr = blockIdx.x - 1 - (blockIdx.x >> 4);   // 0..239 (bid%16!=0)
    for (int s = wkr; s < NSAMP; s += MEGA_BLOCKS - FPSB) {
      if (t == 0) {
        unsigned v = __hip_atomic_load((const unsigned*)&sampled[s],
                        __ATOMIC_RELAXED, __HIP_MEMORY_SCOPE_AGENT);
        while (v == 0xFFFFFFFFu) {
          __builtin_amdgcn_s_sleep(64);
          v = __hip_atomic_load((const unsigned*)&sampled[s],
                  __ATOMIC_RELAXED, __HIP_MEMORY_SCOPE_AGENT);
        }
        binfo[2] = (int)(v & 0xFFFFu);
        ctl[0] = 0u; ctl[1] = 0u;
      }
      for (int k = t; k < 8192; k += 1024) hist[k] = 0u;
      __syncthreads();
      const int sid = binfo[2];
      float4 c4 = xyzw[sid];
      const float cx=c4.x, cy=c4.y, cz=c4.z, c2=c4.w;
      for (int i = 0; i < N_PTS/1024; ++i) {
        int j = i*1024 + t;
        float4 p = xyzw[j];
        float dot = __fadd_rn(__fadd_rn(__fmul_rn(cx,p.x),__fmul_rn(cy,p.y)),__fmul_rn(cz,p.z));
        float d = __fsub_rn(__fadd_rn(c2, p.w), __fmul_rn(2.0f, dot));
        unsigned kb = __float_as_uint(d);
        kb ^= ((unsigned)((int)kb >> 31)) | 0x80000000u;
        atomicAdd(&hist[kb >> 19], 1u);
      }
      __syncthreads();
      unsigned ch = 0u;
      for (int k = 0; k < 8; ++k) ch += hist[t*8 + k];
      scan[t] = ch;
      __syncthreads();
      for (int off = 1; off < 1024; off <<= 1) {
        unsigned vv = (t >= off) ? scan[t - off] : 0u;
        __syncthreads();
        scan[t] += vv;
        __syncthreads();
      }
      unsigned inc = scan[t], before = inc - ch;
      if (before < NGRP && inc >= NGRP) {
        unsigned c = before;
        for (int k = 0; k < 8; ++k) {
          unsigned nb = hist[t*8 + k];
          if (c + nb >= NGRP) { binfo[0] = t*8 + k; binfo[1] = (int)c; break; }
          c += nb;
        }
      }
      __syncthreads();
      const unsigned B = (unsigned)binfo[0];
      const int bef = binfo[1];
      for (int i = 0; i < N_PTS/1024; ++i) {
        int j = i*1024 + t;
        float4 p = xyzw[j];
        float dot = __fadd_rn(__fadd_rn(__fmul_rn(cx,p.x),__fmul_rn(cy,p.y)),__fmul_rn(cz,p.z));
        float d = __fsub_rn(__fadd_rn(c2, p.w), __fmul_rn(2.0f, dot));
        unsigned kb = __float_as_uint(d);
        kb ^= ((unsigned)((int)kb >> 31)) | 0x80000000u;
        unsigned bin = kb >> 19;
        if (bin < B) {
          unsigned pos = atomicAdd(&ctl[0], 1u);
          groups[s*NGRP + pos] = j;
        } else if (bin == B) {
          unsigned ci = atomicAdd(&ctl[1], 1u);
          if (ci < GB_CAND) { candK[ci] = kb; candI[ci] = j; }
        }
      }
      __syncthreads();
      int M = ctl[1] < GB_CAND ? (int)ctl[1] : GB_CAND;
      int need = NGRP - bef;
      for (int c = t; c < M; c += 1024) {
        unsigned mk = candK[c]; int mi = candI[c];
        int rank = 0;
        for (int q = 0; q < M; ++q) {
          unsigned qk = candK[q];
          rank += (qk < mk || (qk == mk && candI[q] < mi)) ? 1 : 0;
        }
        if (rank < need) {
          unsigned pos = atomicAdd(&ctl[0], 1u);
          groups[s*NGRP + pos] = candI[c];
        }
      }
      __syncthreads();
      if (t == 0) {
        while (ctl[0] < NGRP) { groups[s*NGRP + ctl[0]] = 0; ctl[0]++; }
      }
      __syncthreads();
      if (t < DIMS) cf[t] = pts[sid*6 + t];
      __syncthreads();
      if (t < NGRP) {
        int g = groups[s*NGRP + t];
#pragma unroll
        for (int k = 0; k < DIMS; ++k) {
          float v = pts[g*6 + k];
          feat[t*12 + k] = v - cf[k];
          feat[t*12 + 6 + k] = v;
        }
      }
      __syncthreads();
      if (t < EMB) {
        float w[12];
#pragma unroll
        for (int k = 0; k < 12; ++k) w[k] = W1[k*EMB + t];
        float b = b1[t];
        float sum = 0.f, ss = 0.f;
        for (int r = 0; r < NGRP; ++r) {
          float y = b;
#pragma unroll
          for (int k = 0; k < 12; ++k) y += feat[r*12+k] * w[k];
          sum += y; ss += y*y;
        }
        atomicAdd(&gsum[t], sum);
        atomicAdd(&gss[t], ss);
      }
      __syncthreads();   // smraw reused next s
    }
  }
}

// ---------------- bn1 finalize ----------------------------------------------
__global__ __launch_bounds__(EMB) void k_finalize(const float* __restrict__ gsum,
    const float* __restrict__ gss, const float* __restrict__ scale,
    const float* __restrict__ bias, float* __restrict__ ac) {
  int c = threadIdx.x;
  float inv = 1.f / (float)ROWS;
  float mean = gsum[c] * inv;
  float var = gss[c] * inv - mean*mean;
  var = var < 0.f ? 0.f : var;
  float a = scale[c] * rsqrtf(var + EPS_BN);
  ac[c] = a; ac[EMB + c] = bias[c] - mean * a;
}

// ---------------- bn2 finalize from 32-sliced stats -------------------------
__global__ __launch_bounds__(EMB) void k_finalize2(const float* __restrict__ st2,
    const float* __restrict__ scale, const float* __restrict__ bias,
    float* __restrict__ ac) {
  int c = threadIdx.x;
  float sum = 0.f, ss = 0.f;
  for (int i = 0; i < 32; ++i) {
    sum += st2[i*1024 + c];
    ss  += st2[i*1024 + 512 + c];
  }
  float inv = 1.f / (float)ROWS;
  float mean = sum * inv;
  float var = ss * inv - mean*mean;
  var = var < 0.f ? 0.f : var;
  float a = scale[c] * rsqrtf(var + EPS_BN);
  ac[c] = a; ac[EMB + c] = bias[c] - mean * a;
}

// ---------------- fused MLP: fp32 GEMM1 -> bf16 MFMA GEMM2 ------------------
__global__ __launch_bounds__(512, 4) void k_mlp(const float* __restrict__ pts,
    const int* __restrict__ sampled, const int* __restrict__ groups,
    const float* __restrict__ W1, const float* __restrict__ b1,
    const float* __restrict__ ac1, const unsigned short* __restrict__ W2T,
    const float* __restrict__ b2, const float* __restrict__ scale2,
    float* __restrict__ st2, float* __restrict__ y2sel) {
  const int s = blockIdx.x, t = threadIdx.x;
  extern __shared__ __align__(16) char smc[];
  float* feat = (float*)smc;                       // 768 f
  float* cf   = (float*)(smc + 3072);              // 8 f
  unsigned short* h1b = (unsigned short*)(smc + 3104);  // 64 x 520 bf16
  if (t < DIMS) cf[t] = pts[(sampled[s] & 0xFFFF)*6 + t];
  __syncthreads();
  if (t < NGRP) {
    int g = groups[s*NGRP + t];
#pragma unroll
    for (int k = 0; k < DIMS; ++k) {
      float v = pts[g*6 + k];
      feat[t*12+k]   = v - cf[k];
      feat[t*12+6+k] = v;
    }
  }
  __syncthreads();
  {
    float w[12];
#pragma unroll
    for (int k = 0; k < 12; ++k) w[k] = W1[k*EMB + t];
    float b = b1[t], a1 = ac1[t], c1 = ac1[EMB + t];
    for (int r = 0; r < NGRP; ++r) {
      float y = b;
#pragma unroll
      for (int k = 0; k < 12; ++k) y += feat[r*12+k] * w[k];
      float hv = a1*y + c1;
      h1b[r*H1B_S + t] = f2bf(hv > 0.f ? hv : 0.f);
    }
  }
  __syncthreads();
  const int lane = t & 63, w = t >> 6;
  const int quad = lane >> 4, l16 = lane & 15;
  float4v acc[4][4];
#pragma unroll
  for (int nt = 0; nt < 4; ++nt) {
    float bv = b2[(w*4+nt)*16 + l16];
#pragma unroll
    for (int mt = 0; mt < 4; ++mt)
      acc[nt][mt] = (float4v){bv, bv, bv, bv};
  }
  for (int kc = 0; kc < 16; ++kc) {
    const int kb = kc*32 + quad*8;
    short8 af[4];
#pragma unroll
    for (int mt = 0; mt < 4; ++mt)
      af[mt] = *(const short8*)&h1b[(mt*16 + l16)*H1B_S + kb];
#pragma unroll
    for (int nt = 0; nt < 4; ++nt) {
      const int c = (w*4+nt)*16 + l16;
      short8 bf = *(const short8*)&W2T[c*EMB + kb];
#pragma unroll
      for (int mt = 0; mt < 4; ++mt)
        acc[nt][mt] = __builtin_amdgcn_mfma_f32_16x16x32_bf16(af[mt], bf, acc[nt][mt], 0, 0, 0);
    }
  }
#pragma unroll
  for (int nt = 0; nt < 4; ++nt) {
    float sm_ = 0.f, ss_ = 0.f, mx = -__builtin_inff(), mn = __builtin_inff();
#pragma unroll
    for (int mt = 0; mt < 4; ++mt)
#pragma unroll
      for (int i = 0; i < 4; ++i) {
        float v = acc[nt][mt][i];
        sm_ += v; ss_ += v*v;
        mx = fmaxf(mx, v); mn = fminf(mn, v);
      }
#pragma unroll
    for (int off = 16; off <= 32; off <<= 1) {
      sm_ += __shfl_xor(sm_, off, 64);
      ss_ += __shfl_xor(ss_, off, 64);
      mx = fmaxf(mx, __shfl_xor(mx, off, 64));
      mn = fminf(mn, __shfl_xor(mn, off, 64));
    }
    if (quad == 0) {
      int c = (w*4+nt)*16 + l16;
      atomicAdd(&st2[(s & 31)*1024 + c], sm_);
      atomicAdd(&st2[(s & 31)*1024 + 512 + c], ss_);
      y2sel[s*EMB + c] = (scale2[c] >= 0.f) ? mx : mn;
    }
  }
}

// ---------------- epilogue: bn2+relu on pooled extremum ---------------------
__global__ __launch_bounds__(256) void k_out(const float* __restrict__ y2sel,
    const float* __restrict__ ac2, float* __restrict__ out) {
  int i = blockIdx.x*256 + threadIdx.x;
  int c = i & (EMB-1);
  float a = ac2[c], cc = ac2[EMB + c];
  float v = a*y2sel[i] + cc;
  out[i] = v > 0.f ? v : 0.f;
}

extern "C" void kernel_launch(void* const* d_in, const int* in_sizes, int n_in,
                              void* d_out, int out_size, void* d_ws, size_t ws_size,
                              hipStream_t stream) {
  const float* pts    = (const float*)d_in[0];
  const float* W1     = (const float*)d_in[1];
  const float* b1     = (const float*)d_in[2];
  const float* scale1 = (const float*)d_in[3];
  const float* bias1  = (const float*)d_in[4];
  const float* W2     = (const float*)d_in[5];
  const float* b2     = (const float*)d_in[6];
  const float* scale2 = (const float*)d_in[7];
  const float* bias2  = (const float*)d_in[8];
  const int*   seed   = (const int*)d_in[9];
  float* out = (float*)d_out;

  char* ws = (char*)d_ws;
  int*    sampled = (int*)(ws);
  int*    groups  = (int*)(ws + 8192);
  float4* xyzw    = (float4*)(ws + 532480);
  float*  stats   = (float*)(ws + 1581056);
  float* gsum1 = stats, *gss1 = stats + 512;
  float*  ac1     = (float*)(ws + 1589248);
  float*  ac2     = (float*)(ws + 1593344);
  float*  y2sel   = (float*)(ws + 1597440);          // 4 MB
  // slot+mirror alias y2sel (disjoint lifetime): 2*32752 u64 = 524KB < 4MB
  unsigned long long* slot = (unsigned long long*)(ws + 1597440);
  unsigned short* W2T = (unsigned short*)(ws + 5791744);   // 512 KB bf16
  float* st2      = (float*)(ws + 6316032);          // 32 x 1024 sliced bn2 stats

  k_init<<<256, 256, 0, stream>>>(pts, W2, seed, slot, stats, st2, W2T, xyzw, sampled);
  k_mega<<<MEGA_BLOCKS, 1024, MEGA_LDS, stream>>>(xyzw, pts, W1, b1, slot, sampled,
                                                  groups, gsum1, gss1);
  k_finalize<<<1, EMB, 0, stream>>>(gsum1, gss1, scale1, bias1, ac1);
  size_t mlp_lds = 3104 + (size_t)NGRP * H1B_S * sizeof(unsigned short);  // ~68 KB
  k_mlp<<<NSAMP, 512, mlp_lds, stream>>>(pts, sampled, groups, W1, b1, ac1,
                                         W2T, b2, scale2, st2, y2sel);
  k_finalize2<<<1, EMB, 0, stream>>>(st2, scale2, bias2, ac2);
  k_out<<<(out_size+255)/256, 256, 0, stream>>>(y2sel, ac2, out);
}